// Round 1
// 140.507 us; speedup vs baseline: 1.0158x; 1.0158x over previous
//
#include <hip/hip_runtime.h>
#include <math.h>

// TOF PET forward projection.
// History: R3 97us proj, FETCH 215MB (L2 thrash) -> R4 Morton sort: FETCH
// 26MB -> R5 bucket atomic-storm bug (146us) -> R6 fix + 4 lanes/LOR: proj
// 67us, total 146us. R6 proved proj is latency-bound, not VALU-bound (more
// total work than R5 but 1.6x faster).
// R7: (a) scatter materializes SORTED ray records (tmin/span/L/jlo/jhi +
// p1/p2/tof/orig) so proj has zero setup and coalesced LOR reads; (b) 8
// lanes/LOR (~3x wave oversubscription, ~4 trips/lane); (c) /128 -> *0.0078125
// (bit-identical, power of 2) and /900 -> mul (weight path, invisible on bf16
// comparison grid). The 3 voxel /3.125 divides stay IEEE '/' (index-critical).
// R8: proj measured VALU-issue-bound (VALUBusy 74%, HBM 6%). The 3 exact-rn
// divides (~10 VALU ops each, vcc-serialized) are ~40% of the loop body.
// Replace with exact fast path: q = xs*0.32f agrees with rn(xs/3.125) to
// <2.3e-5 abs; floor can only differ within 1e-4 of an integer boundary, so
// take mul+floor when frac(q) in (1e-4, 1-1e-4) and fall back to the true
// IEEE '/' otherwise (~2e-4/coord). Voxel index stays BIT-IDENTICAL to ref.
// Index-path math is STRICTLY UNFUSED exact-rn f32 (numpy semantics) — DO NOT
// approximate or contract (R0-R2: FMA/ulp deviations => voxel flips =>
// absmax 0.14 > 0.071 threshold). fp contract(off) + plain ops + plain '/'.
// Summation order is free (R4 butterfly / R5 sequential / R6 4-lane tree all
// scored absmax 0.015625 = 1 bf16 ulp comparison floor).

#define NB_POS 4096          // 16^3 Morton cells, 25 mm
#define NCLS   8             // window-length classes (16-sample bins)
#define NBUCK  (NB_POS * NCLS)
#define SPL    8             // lanes per LOR

__device__ __forceinline__ int morton4(int x, int y, int z) {
    int m = 0;
#pragma unroll
    for (int b = 0; b < 4; ++b) {
        m |= ((x >> b) & 1) << (3 * b + 0);
        m |= ((y >> b) & 1) << (3 * b + 1);
        m |= ((z >> b) & 1) << (3 * b + 2);
    }
    return m;
}

// Voxel index: bit-identical to (int)floorf(xs / 3.125f) (exact rn div).
// Fast path: xs*0.32f differs from rn(xs/3.125) by < 2.3e-5 abs (xs<=400,
// q<=128: rel err <= 1.5e-7). floor() of the two can only disagree when
// frac(q) is within that distance of 0 or 1 -> guard band 1e-4 (4.3x margin)
// and re-do the true IEEE divide there (~2e-4 probability per coord).
__device__ __forceinline__ int vox_of(float xs) {
#pragma clang fp contract(off)
    float q  = xs * 0.32f;
    float fq = floorf(q);
    float f  = q - fq;                      // exact (Sterbenz-range)
    if (__builtin_expect(f < 1e-4f || f > 0.9999f, 0)) {
        fq = floorf(xs / 3.125f);           // exact rn div — rare path
    }
    return min(max((int)fq, 0), 127);
}

// Slab clip shared by bucket/scatter (strictly unfused, exact rn divs —
// produces the tmin/span the reference sees).
__device__ __forceinline__ void slab_clip(
    float p1x, float p1y, float p1z, float dx, float dy, float dz,
    float& tmin, float& tmax)
{
    const float eps = 1e-8f;
    float sdx = (fabsf(dx) < eps) ? eps : dx;
    float sdy = (fabsf(dy) < eps) ? eps : dy;
    float sdz = (fabsf(dz) < eps) ? eps : dz;
    float tax = (-200.f - p1x) / sdx, tbx = (200.f - p1x) / sdx;
    float tay = (-200.f - p1y) / sdy, tby = (200.f - p1y) / sdy;
    float taz = (-200.f - p1z) / sdz, tbz = (200.f - p1z) / sdz;
    tmin = fmaxf(fmaxf(fmaxf(fminf(tax, tbx), fminf(tay, tby)),
                       fminf(taz, tbz)), 0.f);
    tmax = fminf(fminf(fminf(fmaxf(tax, tbx), fmaxf(tay, tby)),
                       fmaxf(taz, tbz)), 1.f);
}

__global__ void bucket_kernel(const float* __restrict__ lors,
                              int* __restrict__ counts,
                              int* __restrict__ tmp, int n) {
#pragma clang fp contract(off)
    int i = blockIdx.x * 256 + threadIdx.x;
    if (i >= n) return;
    const float* lp = lors + (size_t)i * 7;
    float p1x = lp[0], p1y = lp[1], p1z = lp[2];
    float dx = lp[3] - p1x, dy = lp[4] - p1y, dz = lp[5] - p1z;
    float tt = lp[6];
    float L = sqrtf(((dx * dx) + (dy * dy)) + (dz * dz));

    float tmin, tmax;
    slab_clip(p1x, p1y, p1z, dx, dy, dz, tmin, tmax);

    unsigned key;
    if (!(tmax > tmin) || !(L > 0.f)) {
        // Invalids: spread uniformly (kills R5's one-bucket atomic storm).
        key = (unsigned)i & (NBUCK - 1);
    } else {
        float span = tmax - tmin;
        // TOF-center cell (sort key only; approx math OK here)
        float tc = fminf(fmaxf(0.5f + tt / L, tmin), tmax);
        float px = p1x + tc * dx, py = p1y + tc * dy, pz = p1z + tc * dz;
        int cx = (int)fminf(fmaxf((px + 200.f) * 0.04f, 0.f), 15.f);
        int cy = (int)fminf(fmaxf((py + 200.f) * 0.04f, 0.f), 15.f);
        int cz = (int)fminf(fmaxf((pz + 200.f) * 0.04f, 0.f), 15.f);
        // window length -> 3-bit class (16-sample bins): wave-uniform trips
        float jl = ((0.5f + (tt - 90.f) / L) - tmin) / span * 128.f;
        float jh = ((0.5f + (tt + 90.f) / L) - tmin) / span * 128.f;
        jl = fmaxf(jl, 0.f); jh = fminf(jh, 128.f);
        float wlen = fmaxf(jh - jl, 0.f);
        int cls = min(NCLS - 1, (int)(wlen * (1.f / 16.f)));
        key = ((unsigned)morton4(cx, cy, cz) << 3) | (unsigned)cls;
    }
    atomicAdd(&counts[key], 1);
    tmp[i] = (int)key;
}

__global__ void scan_kernel(const int* __restrict__ counts,
                            int* __restrict__ offsets) {
    __shared__ int s[1024];
    int t = threadIdx.x;
    const int PER = NBUCK / 1024;
    int base = t * PER;
    int local[PER];
    int sum = 0;
#pragma unroll
    for (int i = 0; i < PER; ++i) { local[i] = counts[base + i]; sum += local[i]; }
    s[t] = sum;
    __syncthreads();
    for (int off = 1; off < 1024; off <<= 1) {
        int v = (t >= off) ? s[t - off] : 0;
        __syncthreads();
        s[t] += v;
        __syncthreads();
    }
    int excl = (t == 0) ? 0 : s[t - 1];
#pragma unroll
    for (int i = 0; i < PER; ++i) { offsets[base + i] = excl; excl += local[i]; }
}

// Scatter + setup: computes per-LOR ray record once, writes SORTED arrays.
__global__ void scatter_kernel(const float* __restrict__ lors,
                               const int* __restrict__ tmp,
                               int* __restrict__ offsets,
                               float4* __restrict__ recS,   // {tmin,span,L,pack}
                               float4* __restrict__ ls8,    // 2 per LOR
                               int n) {
#pragma clang fp contract(off)
    int i = blockIdx.x * 256 + threadIdx.x;
    if (i >= n) return;
    const float* lp = lors + (size_t)i * 7;
    float p1x = lp[0], p1y = lp[1], p1z = lp[2];
    float p2x = lp[3], p2y = lp[4], p2z = lp[5];
    float tt = lp[6];
    float dx = p2x - p1x, dy = p2y - p1y, dz = p2z - p1z;
    float L = sqrtf(((dx * dx) + (dy * dy)) + (dz * dz));

    float tmin, tmax;
    slab_clip(p1x, p1y, p1z, dx, dy, dz, tmin, tmax);

    float span, recL;
    int jlo, jhi;
    if (!(tmax > tmin) || !(L > 0.f)) {
        // invalid or degenerate (L==0 => step==0 => out 0 regardless)
        tmin = 0.f; span = 0.f; recL = 0.f; jlo = 0; jhi = -1;
    } else {
        span = tmax - tmin;
        recL = L;
        // Closed-form sample range of TOF window, +-2 slop (validated R4-R6);
        // exact per-sample test retained in proj -> identical sample set.
        const float tlo = 0.5f + (tt - 90.0f) / L;
        const float thi = 0.5f + (tt + 90.0f) / L;
        float jl = ((tlo - tmin) / span) * 128.0f - 0.5f;
        float jh = ((thi - tmin) / span) * 128.0f - 0.5f;
        jl = fminf(fmaxf(jl - 2.0f, 0.0f), 127.0f);
        jh = fminf(fmaxf(jh + 2.0f, -1.0f), 127.0f);
        jlo = (int)jl;
        jhi = (int)ceilf(jh);
        if (jhi > 127) jhi = 127;
    }

    int slot = atomicAdd(&offsets[tmp[i]], 1);
    int pk = (jlo << 16) | (jhi & 0xFFFF);
    recS[slot] = make_float4(tmin, span, recL, __int_as_float(pk));
    ls8[2 * slot + 0] = make_float4(p1x, p1y, p1z, p2x);
    ls8[2 * slot + 1] = make_float4(p2y, p2z, tt, __int_as_float(i));
}

__global__ __launch_bounds__(256) void proj_kernel(
    const float* __restrict__ image,
    const float4* __restrict__ recS,
    const float4* __restrict__ ls8,
    float* __restrict__ out,
    int n_lors, int chunks)
{
#pragma clang fp contract(off)
    // XCD swizzle: block b -> XCD (b&7) works the (b&7)-th chunk of sorted order
    const int b = blockIdx.x;
    const int sb = (b & 7) * chunks + (b >> 3);
    const int idx = sb * 256 + (int)threadIdx.x;
    const int gid = idx >> 3;          // sorted LOR slot
    const int s   = idx & 7;           // sub-lane 0..7
    if (gid >= n_lors) return;

    const float4 a  = ls8[2 * gid + 0];
    const float4 c  = ls8[2 * gid + 1];
    const float4 r  = recS[gid];
    const float p1x = a.x, p1y = a.y, p1z = a.z;
    const float dx = a.w - p1x, dy = c.x - p1y, dz = c.y - p1z;
    const float ttof = c.z;
    const int   orig = __float_as_int(c.w);
    const float tmin = r.x, span = r.y, L = r.z;
    const int   pk   = __float_as_int(r.w);
    const int   jlo  = pk >> 16;
    const int   jhi  = (int)(short)(pk & 0xFFFF);

    float acc = 0.0f;
    for (int j = jlo + s; j <= jhi; j += SPL) {
        // frac = (j+0.5)/128: *0.0078125f is bit-identical (power of 2)
        const float frac = ((float)j + 0.5f) * 0.0078125f;
        const float t = tmin + (frac * span);                 // UNFUSED
        const float dev = ((t - 0.5f) * L) - ttof;            // unfused

        if (fabsf(dev) <= 90.0f) {
            const float px = p1x + (t * dx);                  // UNFUSED
            const float py = p1y + (t * dy);
            const float pz = p1z + (t * dz);
            const int vx = vox_of(px + 200.0f);               // == floorf(./3.125)
            const int vy = vox_of(py + 200.0f);
            const int vz = vox_of(pz + 200.0f);

            const float val = image[(((vx << 7) | vy) << 7) | vz];

            // weight path: invisible on bf16 grid; -1/1800 as multiply
            const float w = 0.06649038f *
                            __expf((dev * dev) * (-5.5555556e-4f));
            acc += val * w;
        }
    }

    // combine 8 sub-lanes (summation order free — validated R4/R5/R6)
    acc += __shfl_xor(acc, 1, 64);
    acc += __shfl_xor(acc, 2, 64);
    acc += __shfl_xor(acc, 4, 64);

    if (s == 0) {
        // step = (span*L)/128: *0.0078125f bit-identical
        const float step = (span * L) * 0.0078125f;
        out[orig] = acc * step;
    }
}

// Fallback (ws too small): self-contained thread-per-LOR, unsorted. Correct
// but slower; only taken if the harness workspace is < ~11 MB.
__global__ __launch_bounds__(256) void proj_fallback(
    const float* __restrict__ image,
    const float* __restrict__ lors,
    float* __restrict__ out, int n_lors)
{
#pragma clang fp contract(off)
    const int lor = blockIdx.x * 256 + threadIdx.x;
    if (lor >= n_lors) return;
    const float* lp = lors + (size_t)lor * 7;
    const float p1x = lp[0], p1y = lp[1], p1z = lp[2];
    const float dx = lp[3] - p1x, dy = lp[4] - p1y, dz = lp[5] - p1z;
    const float ttof = lp[6];
    const float L = sqrtf(((dx * dx) + (dy * dy)) + (dz * dz));
    float tmin, tmax;
    slab_clip(p1x, p1y, p1z, dx, dy, dz, tmin, tmax);
    const float span = fmaxf(tmax - tmin, 0.0f);
    if (!(tmax > tmin)) { out[lor] = 0.0f; return; }
    float acc = 0.0f;
    for (int j = 0; j < 128; ++j) {
        const float frac = ((float)j + 0.5f) * 0.0078125f;
        const float t = tmin + (frac * span);
        const float dev = ((t - 0.5f) * L) - ttof;
        if (fabsf(dev) <= 90.0f) {
            const float px = p1x + (t * dx);
            const float py = p1y + (t * dy);
            const float pz = p1z + (t * dz);
            const int vx = vox_of(px + 200.0f);
            const int vy = vox_of(py + 200.0f);
            const int vz = vox_of(pz + 200.0f);
            const float val = image[(((vx << 7) | vy) << 7) | vz];
            const float w = 0.06649038f *
                            __expf((dev * dev) * (-5.5555556e-4f));
            acc += val * w;
        }
    }
    out[lor] = acc * ((span * L) * 0.0078125f);
}

extern "C" void kernel_launch(void* const* d_in, const int* in_sizes, int n_in,
                              void* d_out, int out_size, void* d_ws, size_t ws_size,
                              hipStream_t stream) {
    const float* image = (const float*)d_in[0];   // 128^3 fp32
    const float* lors  = (const float*)d_in[1];   // N x 7 fp32
    float* out = (float*)d_out;                   // N fp32
    const int n = in_sizes[1] / 7;

    // ws layout: counts[NBUCK] | offsets[NBUCK] | tmp[n] | (16B align)
    //            recS[n]x16B | ls8[2n]x16B
    char* base = (char*)d_ws;
    int* counts  = (int*)base;
    int* offsets = counts + NBUCK;
    int* tmp     = offsets + NBUCK;
    size_t off = (size_t)(2 * NBUCK + n) * sizeof(int);
    off = (off + 15) & ~(size_t)15;
    float4* recS = (float4*)(base + off);
    float4* ls8  = (float4*)(base + off + (size_t)n * 16);
    const size_t need = off + (size_t)n * 48;
    const bool do_sort = (ws_size >= need);

    if (do_sort) {
        hipMemsetAsync(counts, 0, NBUCK * sizeof(int), stream);
        bucket_kernel<<<(n + 255) / 256, 256, 0, stream>>>(lors, counts, tmp, n);
        scan_kernel<<<1, 1024, 0, stream>>>(counts, offsets);
        scatter_kernel<<<(n + 255) / 256, 256, 0, stream>>>(lors, tmp, offsets,
                                                            recS, ls8, n);
        const int nthreads = n * SPL;
        const int nblocks = (nthreads + 255) / 256;
        const int nb8 = ((nblocks + 7) / 8) * 8;
        proj_kernel<<<nb8, 256, 0, stream>>>(image, recS, ls8, out, n, nb8 >> 3);
    } else {
        proj_fallback<<<(n + 255) / 256, 256, 0, stream>>>(image, lors, out, n);
    }
}

// Round 2
// 139.925 us; speedup vs baseline: 1.0201x; 1.0042x over previous
//
#include <hip/hip_runtime.h>
#include <math.h>

// TOF PET forward projection.
// History: R3 97us proj, FETCH 215MB (L2 thrash) -> R4 Morton sort: FETCH
// 26MB -> R5 bucket atomic-storm bug (146us) -> R6 fix + 4 lanes/LOR: proj
// 67us, total 146us -> R7 sorted record materialization + 8 lanes/LOR: proj
// 50us -> R8 exact-fast-path voxel divide: proj 44.5us, VALUBusy 74->54%.
// R9: proj is now LATENCY-bound (VALUBusy 54%, HBM 7%): divergent window
// branch around the image load + unknown-trip loop kept MLP=1/lane. Fix:
// (a) branchless predication (indices always clamped-valid; acc += val*0 is
// exact; slop region <=4 samples so extra loads negligible); (b) manual 2x
// unroll, dual accumulators, both loads issued before either waitcnt ->
// MLP=2/lane. Summation order free (validated R4/R5/R6).
// Index-path math is STRICTLY UNFUSED exact-rn f32 (numpy semantics) — DO NOT
// approximate or contract (R0-R2: FMA/ulp deviations => voxel flips =>
// absmax 0.14 > 0.071 threshold). fp contract(off) + plain ops + plain '/'.
// vox fast path (R8): q=xs*0.32f agrees with rn(xs/3.125) to <2.3e-5; floor
// can only differ within 1e-4 of an integer boundary -> exact IEEE '/'
// fallback there (~2e-4/coord). Voxel index stays BIT-IDENTICAL to ref.

#define NB_POS 4096          // 16^3 Morton cells, 25 mm
#define NCLS   8             // window-length classes (16-sample bins)
#define NBUCK  (NB_POS * NCLS)
#define SPL    8             // lanes per LOR

__device__ __forceinline__ int morton4(int x, int y, int z) {
    int m = 0;
#pragma unroll
    for (int b = 0; b < 4; ++b) {
        m |= ((x >> b) & 1) << (3 * b + 0);
        m |= ((y >> b) & 1) << (3 * b + 1);
        m |= ((z >> b) & 1) << (3 * b + 2);
    }
    return m;
}

// Voxel index: bit-identical to (int)floorf(xs / 3.125f) (exact rn div).
// Fast path: xs*0.32f differs from rn(xs/3.125) by < 2.3e-5 abs (xs<=400,
// q<=128: rel err <= 1.5e-7). floor() of the two can only disagree when
// frac(q) is within that distance of 0 or 1 -> guard band 1e-4 (4.3x margin)
// and re-do the true IEEE divide there (~2e-4 probability per coord).
__device__ __forceinline__ int vox_of(float xs) {
#pragma clang fp contract(off)
    float q  = xs * 0.32f;
    float fq = floorf(q);
    float f  = q - fq;                      // exact (Sterbenz-range)
    if (__builtin_expect(f < 1e-4f || f > 0.9999f, 0)) {
        fq = floorf(xs / 3.125f);           // exact rn div — rare path
    }
    return min(max((int)fq, 0), 127);
}

// Slab clip shared by bucket/scatter (strictly unfused, exact rn divs —
// produces the tmin/span the reference sees).
__device__ __forceinline__ void slab_clip(
    float p1x, float p1y, float p1z, float dx, float dy, float dz,
    float& tmin, float& tmax)
{
    const float eps = 1e-8f;
    float sdx = (fabsf(dx) < eps) ? eps : dx;
    float sdy = (fabsf(dy) < eps) ? eps : dy;
    float sdz = (fabsf(dz) < eps) ? eps : dz;
    float tax = (-200.f - p1x) / sdx, tbx = (200.f - p1x) / sdx;
    float tay = (-200.f - p1y) / sdy, tby = (200.f - p1y) / sdy;
    float taz = (-200.f - p1z) / sdz, tbz = (200.f - p1z) / sdz;
    tmin = fmaxf(fmaxf(fmaxf(fminf(tax, tbx), fminf(tay, tby)),
                       fminf(taz, tbz)), 0.f);
    tmax = fminf(fminf(fminf(fmaxf(tax, tbx), fmaxf(tay, tby)),
                       fmaxf(taz, tbz)), 1.f);
}

__global__ void bucket_kernel(const float* __restrict__ lors,
                              int* __restrict__ counts,
                              int* __restrict__ tmp, int n) {
#pragma clang fp contract(off)
    int i = blockIdx.x * 256 + threadIdx.x;
    if (i >= n) return;
    const float* lp = lors + (size_t)i * 7;
    float p1x = lp[0], p1y = lp[1], p1z = lp[2];
    float dx = lp[3] - p1x, dy = lp[4] - p1y, dz = lp[5] - p1z;
    float tt = lp[6];
    float L = sqrtf(((dx * dx) + (dy * dy)) + (dz * dz));

    float tmin, tmax;
    slab_clip(p1x, p1y, p1z, dx, dy, dz, tmin, tmax);

    unsigned key;
    if (!(tmax > tmin) || !(L > 0.f)) {
        // Invalids: spread uniformly (kills R5's one-bucket atomic storm).
        key = (unsigned)i & (NBUCK - 1);
    } else {
        float span = tmax - tmin;
        // TOF-center cell (sort key only; approx math OK here)
        float tc = fminf(fmaxf(0.5f + tt / L, tmin), tmax);
        float px = p1x + tc * dx, py = p1y + tc * dy, pz = p1z + tc * dz;
        int cx = (int)fminf(fmaxf((px + 200.f) * 0.04f, 0.f), 15.f);
        int cy = (int)fminf(fmaxf((py + 200.f) * 0.04f, 0.f), 15.f);
        int cz = (int)fminf(fmaxf((pz + 200.f) * 0.04f, 0.f), 15.f);
        // window length -> 3-bit class (16-sample bins): wave-uniform trips
        float jl = ((0.5f + (tt - 90.f) / L) - tmin) / span * 128.f;
        float jh = ((0.5f + (tt + 90.f) / L) - tmin) / span * 128.f;
        jl = fmaxf(jl, 0.f); jh = fminf(jh, 128.f);
        float wlen = fmaxf(jh - jl, 0.f);
        int cls = min(NCLS - 1, (int)(wlen * (1.f / 16.f)));
        key = ((unsigned)morton4(cx, cy, cz) << 3) | (unsigned)cls;
    }
    atomicAdd(&counts[key], 1);
    tmp[i] = (int)key;
}

__global__ void scan_kernel(const int* __restrict__ counts,
                            int* __restrict__ offsets) {
    __shared__ int s[1024];
    int t = threadIdx.x;
    const int PER = NBUCK / 1024;
    int base = t * PER;
    int local[PER];
    int sum = 0;
#pragma unroll
    for (int i = 0; i < PER; ++i) { local[i] = counts[base + i]; sum += local[i]; }
    s[t] = sum;
    __syncthreads();
    for (int off = 1; off < 1024; off <<= 1) {
        int v = (t >= off) ? s[t - off] : 0;
        __syncthreads();
        s[t] += v;
        __syncthreads();
    }
    int excl = (t == 0) ? 0 : s[t - 1];
#pragma unroll
    for (int i = 0; i < PER; ++i) { offsets[base + i] = excl; excl += local[i]; }
}

// Scatter + setup: computes per-LOR ray record once, writes SORTED arrays.
__global__ void scatter_kernel(const float* __restrict__ lors,
                               const int* __restrict__ tmp,
                               int* __restrict__ offsets,
                               float4* __restrict__ recS,   // {tmin,span,L,pack}
                               float4* __restrict__ ls8,    // 2 per LOR
                               int n) {
#pragma clang fp contract(off)
    int i = blockIdx.x * 256 + threadIdx.x;
    if (i >= n) return;
    const float* lp = lors + (size_t)i * 7;
    float p1x = lp[0], p1y = lp[1], p1z = lp[2];
    float p2x = lp[3], p2y = lp[4], p2z = lp[5];
    float tt = lp[6];
    float dx = p2x - p1x, dy = p2y - p1y, dz = p2z - p1z;
    float L = sqrtf(((dx * dx) + (dy * dy)) + (dz * dz));

    float tmin, tmax;
    slab_clip(p1x, p1y, p1z, dx, dy, dz, tmin, tmax);

    float span, recL;
    int jlo, jhi;
    if (!(tmax > tmin) || !(L > 0.f)) {
        // invalid or degenerate (L==0 => step==0 => out 0 regardless)
        tmin = 0.f; span = 0.f; recL = 0.f; jlo = 0; jhi = -1;
    } else {
        span = tmax - tmin;
        recL = L;
        // Closed-form sample range of TOF window, +-2 slop (validated R4-R6);
        // exact per-sample test retained in proj -> identical sample set.
        const float tlo = 0.5f + (tt - 90.0f) / L;
        const float thi = 0.5f + (tt + 90.0f) / L;
        float jl = ((tlo - tmin) / span) * 128.0f - 0.5f;
        float jh = ((thi - tmin) / span) * 128.0f - 0.5f;
        jl = fminf(fmaxf(jl - 2.0f, 0.0f), 127.0f);
        jh = fminf(fmaxf(jh + 2.0f, -1.0f), 127.0f);
        jlo = (int)jl;
        jhi = (int)ceilf(jh);
        if (jhi > 127) jhi = 127;
    }

    int slot = atomicAdd(&offsets[tmp[i]], 1);
    int pk = (jlo << 16) | (jhi & 0xFFFF);
    recS[slot] = make_float4(tmin, span, recL, __int_as_float(pk));
    ls8[2 * slot + 0] = make_float4(p1x, p1y, p1z, p2x);
    ls8[2 * slot + 1] = make_float4(p2y, p2z, tt, __int_as_float(i));
}

__global__ __launch_bounds__(256) void proj_kernel(
    const float* __restrict__ image,
    const float4* __restrict__ recS,
    const float4* __restrict__ ls8,
    float* __restrict__ out,
    int n_lors, int chunks)
{
#pragma clang fp contract(off)
    // XCD swizzle: block b -> XCD (b&7) works the (b&7)-th chunk of sorted order
    const int b = blockIdx.x;
    const int sb = (b & 7) * chunks + (b >> 3);
    const int idx = sb * 256 + (int)threadIdx.x;
    const int gid = idx >> 3;          // sorted LOR slot
    const int s   = idx & 7;           // sub-lane 0..7
    if (gid >= n_lors) return;

    const float4 a  = ls8[2 * gid + 0];
    const float4 c  = ls8[2 * gid + 1];
    const float4 r  = recS[gid];
    const float p1x = a.x, p1y = a.y, p1z = a.z;
    const float dx = a.w - p1x, dy = c.x - p1y, dz = c.y - p1z;
    const float ttof = c.z;
    const int   orig = __float_as_int(c.w);
    const float tmin = r.x, span = r.y, L = r.z;
    const int   pk   = __float_as_int(r.w);
    const int   jlo  = pk >> 16;
    const int   jhi  = (int)(short)(pk & 0xFFFF);

    // Branchless body: voxel indices are clamped-valid regardless of the TOF
    // window test, so the image load is unconditional (cheap: slop region is
    // <=4 samples/LOR) and masked via w=0 (acc += val*0 is exact).
    // 2x unroll: two independent chains, both loads in flight -> MLP=2/lane.
    float acc0 = 0.0f, acc1 = 0.0f;
    int j = jlo + s;
    for (; j + SPL <= jhi; j += 2 * SPL) {
        const int ja = j, jb = j + SPL;
        const float fra = ((float)ja + 0.5f) * 0.0078125f;   // /128 exact
        const float frb = ((float)jb + 0.5f) * 0.0078125f;
        const float ta = tmin + (fra * span);                // UNFUSED
        const float tb = tmin + (frb * span);
        const float da = ((ta - 0.5f) * L) - ttof;           // unfused
        const float db = ((tb - 0.5f) * L) - ttof;

        const float pax = p1x + (ta * dx);                   // UNFUSED
        const float pay = p1y + (ta * dy);
        const float paz = p1z + (ta * dz);
        const float pbx = p1x + (tb * dx);
        const float pby = p1y + (tb * dy);
        const float pbz = p1z + (tb * dz);

        const int ia = (((vox_of(pax + 200.0f) << 7) | vox_of(pay + 200.0f)) << 7)
                       | vox_of(paz + 200.0f);
        const int ib = (((vox_of(pbx + 200.0f) << 7) | vox_of(pby + 200.0f)) << 7)
                       | vox_of(pbz + 200.0f);

        const float va = image[ia];
        const float vb = image[ib];

        const float wa = (fabsf(da) <= 90.0f)
            ? 0.06649038f * __expf((da * da) * (-5.5555556e-4f)) : 0.0f;
        const float wb = (fabsf(db) <= 90.0f)
            ? 0.06649038f * __expf((db * db) * (-5.5555556e-4f)) : 0.0f;

        acc0 += va * wa;
        acc1 += vb * wb;
    }
    if (j <= jhi) {                                          // <=1 remainder
        const float fr = ((float)j + 0.5f) * 0.0078125f;
        const float t = tmin + (fr * span);
        const float dev = ((t - 0.5f) * L) - ttof;
        const float px = p1x + (t * dx);
        const float py = p1y + (t * dy);
        const float pz = p1z + (t * dz);
        const int vi = (((vox_of(px + 200.0f) << 7) | vox_of(py + 200.0f)) << 7)
                       | vox_of(pz + 200.0f);
        const float val = image[vi];
        const float w = (fabsf(dev) <= 90.0f)
            ? 0.06649038f * __expf((dev * dev) * (-5.5555556e-4f)) : 0.0f;
        acc0 += val * w;
    }
    float acc = acc0 + acc1;   // summation order free (validated R4/R5/R6)

    // combine 8 sub-lanes
    acc += __shfl_xor(acc, 1, 64);
    acc += __shfl_xor(acc, 2, 64);
    acc += __shfl_xor(acc, 4, 64);

    if (s == 0) {
        // step = (span*L)/128: *0.0078125f bit-identical
        const float step = (span * L) * 0.0078125f;
        out[orig] = acc * step;
    }
}

// Fallback (ws too small): self-contained thread-per-LOR, unsorted. Correct
// but slower; only taken if the harness workspace is < ~11 MB.
__global__ __launch_bounds__(256) void proj_fallback(
    const float* __restrict__ image,
    const float* __restrict__ lors,
    float* __restrict__ out, int n_lors)
{
#pragma clang fp contract(off)
    const int lor = blockIdx.x * 256 + threadIdx.x;
    if (lor >= n_lors) return;
    const float* lp = lors + (size_t)lor * 7;
    const float p1x = lp[0], p1y = lp[1], p1z = lp[2];
    const float dx = lp[3] - p1x, dy = lp[4] - p1y, dz = lp[5] - p1z;
    const float ttof = lp[6];
    const float L = sqrtf(((dx * dx) + (dy * dy)) + (dz * dz));
    float tmin, tmax;
    slab_clip(p1x, p1y, p1z, dx, dy, dz, tmin, tmax);
    const float span = fmaxf(tmax - tmin, 0.0f);
    if (!(tmax > tmin)) { out[lor] = 0.0f; return; }
    float acc = 0.0f;
    for (int j = 0; j < 128; ++j) {
        const float frac = ((float)j + 0.5f) * 0.0078125f;
        const float t = tmin + (frac * span);
        const float dev = ((t - 0.5f) * L) - ttof;
        if (fabsf(dev) <= 90.0f) {
            const float px = p1x + (t * dx);
            const float py = p1y + (t * dy);
            const float pz = p1z + (t * dz);
            const int vx = vox_of(px + 200.0f);
            const int vy = vox_of(py + 200.0f);
            const int vz = vox_of(pz + 200.0f);
            const float val = image[(((vx << 7) | vy) << 7) | vz];
            const float w = 0.06649038f *
                            __expf((dev * dev) * (-5.5555556e-4f));
            acc += val * w;
        }
    }
    out[lor] = acc * ((span * L) * 0.0078125f);
}

extern "C" void kernel_launch(void* const* d_in, const int* in_sizes, int n_in,
                              void* d_out, int out_size, void* d_ws, size_t ws_size,
                              hipStream_t stream) {
    const float* image = (const float*)d_in[0];   // 128^3 fp32
    const float* lors  = (const float*)d_in[1];   // N x 7 fp32
    float* out = (float*)d_out;                   // N fp32
    const int n = in_sizes[1] / 7;

    // ws layout: counts[NBUCK] | offsets[NBUCK] | tmp[n] | (16B align)
    //            recS[n]x16B | ls8[2n]x16B
    char* base = (char*)d_ws;
    int* counts  = (int*)base;
    int* offsets = counts + NBUCK;
    int* tmp     = offsets + NBUCK;
    size_t off = (size_t)(2 * NBUCK + n) * sizeof(int);
    off = (off + 15) & ~(size_t)15;
    float4* recS = (float4*)(base + off);
    float4* ls8  = (float4*)(base + off + (size_t)n * 16);
    const size_t need = off + (size_t)n * 48;
    const bool do_sort = (ws_size >= need);

    if (do_sort) {
        hipMemsetAsync(counts, 0, NBUCK * sizeof(int), stream);
        bucket_kernel<<<(n + 255) / 256, 256, 0, stream>>>(lors, counts, tmp, n);
        scan_kernel<<<1, 1024, 0, stream>>>(counts, offsets);
        scatter_kernel<<<(n + 255) / 256, 256, 0, stream>>>(lors, tmp, offsets,
                                                            recS, ls8, n);
        const int nthreads = n * SPL;
        const int nblocks = (nthreads + 255) / 256;
        const int nb8 = ((nblocks + 7) / 8) * 8;
        proj_kernel<<<nb8, 256, 0, stream>>>(image, recS, ls8, out, n, nb8 >> 3);
    } else {
        proj_fallback<<<(n + 255) / 256, 256, 0, stream>>>(image, lors, out, n);
    }
}

// Round 3
// 139.803 us; speedup vs baseline: 1.0209x; 1.0009x over previous
//
#include <hip/hip_runtime.h>
#include <math.h>

// TOF PET forward projection.
// History: R3 97us proj, FETCH 215MB (L2 thrash) -> R4 Morton sort: FETCH
// 26MB -> R5 bucket atomic-storm bug -> R6 fix + 4 lanes/LOR: proj 67us ->
// R7 sorted record materialization + 8 lanes/LOR: proj 50us -> R8 exact-fast-
// path voxel divide: proj 44.5us, VALUBusy 74->54% -> R9 2x unroll +
// branchless: NEUTRAL (45us, VALUBusy 55) — per-sample serial chain
// (t->p->vox->idx->load, ~20 ops) is the limiter, not cross-sample ILP.
// R10: AFFINE fast path. Exact chain per coord is affine in alpha=j+0.5:
// Q = C0 + alpha*C1 (1 FMA). |Q - ref_chain| <= 8e-5 (bound: ref rounds
// within 2.8e-5 of real, Q within 4.8e-5), so floor(Q)==floor(ref) unless
// frac(Q) within 1e-3 of an integer (12x margin) -> per-sample guard
// (min3/max3), rare (~2e-3/coord) fallback recomputes the FULL exact
// unfused chain. Voxel index stays BIT-IDENTICAL to numpy. dev also affine
// (weight path, loose tolerance: boundary flip <= 1.7e-3 << 0.0156 floor).
// Chain before load: 20 ops -> 3; body ~54 -> ~38 VALU ops.
// Index-path math (exact fallback + scatter/bucket) is STRICTLY UNFUSED
// exact-rn f32 — DO NOT approximate or contract (R0-R2: voxel flips =>
// absmax 0.14 > 0.071). fp contract(off); approx path uses explicit fmaf.
// Summation order free (validated R4/R5/R6).

#define NB_POS 4096          // 16^3 Morton cells, 25 mm
#define NCLS   8             // window-length classes (16-sample bins)
#define NBUCK  (NB_POS * NCLS)
#define SPL    8             // lanes per LOR

__device__ __forceinline__ int morton4(int x, int y, int z) {
    int m = 0;
#pragma unroll
    for (int b = 0; b < 4; ++b) {
        m |= ((x >> b) & 1) << (3 * b + 0);
        m |= ((y >> b) & 1) << (3 * b + 1);
        m |= ((z >> b) & 1) << (3 * b + 2);
    }
    return m;
}

// Voxel index for the fallback kernel: bit-identical to
// (int)floorf(xs / 3.125f) (R8-validated exact-fast-path).
__device__ __forceinline__ int vox_of(float xs) {
#pragma clang fp contract(off)
    float q  = xs * 0.32f;
    float fq = floorf(q);
    float f  = q - fq;                      // exact (Sterbenz-range)
    if (__builtin_expect(f < 1e-4f || f > 0.9999f, 0)) {
        fq = floorf(xs / 3.125f);           // exact rn div — rare path
    }
    return min(max((int)fq, 0), 127);
}

// Slab clip shared by bucket/scatter (strictly unfused, exact rn divs —
// produces the tmin/span the reference sees).
__device__ __forceinline__ void slab_clip(
    float p1x, float p1y, float p1z, float dx, float dy, float dz,
    float& tmin, float& tmax)
{
    const float eps = 1e-8f;
    float sdx = (fabsf(dx) < eps) ? eps : dx;
    float sdy = (fabsf(dy) < eps) ? eps : dy;
    float sdz = (fabsf(dz) < eps) ? eps : dz;
    float tax = (-200.f - p1x) / sdx, tbx = (200.f - p1x) / sdx;
    float tay = (-200.f - p1y) / sdy, tby = (200.f - p1y) / sdy;
    float taz = (-200.f - p1z) / sdz, tbz = (200.f - p1z) / sdz;
    tmin = fmaxf(fmaxf(fmaxf(fminf(tax, tbx), fminf(tay, tby)),
                       fminf(taz, tbz)), 0.f);
    tmax = fminf(fminf(fminf(fmaxf(tax, tbx), fmaxf(tay, tby)),
                       fmaxf(taz, tbz)), 1.f);
}

__global__ void bucket_kernel(const float* __restrict__ lors,
                              int* __restrict__ counts,
                              int* __restrict__ tmp, int n) {
#pragma clang fp contract(off)
    int i = blockIdx.x * 256 + threadIdx.x;
    if (i >= n) return;
    const float* lp = lors + (size_t)i * 7;
    float p1x = lp[0], p1y = lp[1], p1z = lp[2];
    float dx = lp[3] - p1x, dy = lp[4] - p1y, dz = lp[5] - p1z;
    float tt = lp[6];
    float L = sqrtf(((dx * dx) + (dy * dy)) + (dz * dz));

    float tmin, tmax;
    slab_clip(p1x, p1y, p1z, dx, dy, dz, tmin, tmax);

    unsigned key;
    if (!(tmax > tmin) || !(L > 0.f)) {
        // Invalids: spread uniformly (kills R5's one-bucket atomic storm).
        key = (unsigned)i & (NBUCK - 1);
    } else {
        float span = tmax - tmin;
        // TOF-center cell (sort key only; approx math OK here)
        float tc = fminf(fmaxf(0.5f + tt / L, tmin), tmax);
        float px = p1x + tc * dx, py = p1y + tc * dy, pz = p1z + tc * dz;
        int cx = (int)fminf(fmaxf((px + 200.f) * 0.04f, 0.f), 15.f);
        int cy = (int)fminf(fmaxf((py + 200.f) * 0.04f, 0.f), 15.f);
        int cz = (int)fminf(fmaxf((pz + 200.f) * 0.04f, 0.f), 15.f);
        // window length -> 3-bit class (16-sample bins): wave-uniform trips
        float jl = ((0.5f + (tt - 90.f) / L) - tmin) / span * 128.f;
        float jh = ((0.5f + (tt + 90.f) / L) - tmin) / span * 128.f;
        jl = fmaxf(jl, 0.f); jh = fminf(jh, 128.f);
        float wlen = fmaxf(jh - jl, 0.f);
        int cls = min(NCLS - 1, (int)(wlen * (1.f / 16.f)));
        key = ((unsigned)morton4(cx, cy, cz) << 3) | (unsigned)cls;
    }
    atomicAdd(&counts[key], 1);
    tmp[i] = (int)key;
}

__global__ void scan_kernel(const int* __restrict__ counts,
                            int* __restrict__ offsets) {
    __shared__ int s[1024];
    int t = threadIdx.x;
    const int PER = NBUCK / 1024;
    int base = t * PER;
    int local[PER];
    int sum = 0;
#pragma unroll
    for (int i = 0; i < PER; ++i) { local[i] = counts[base + i]; sum += local[i]; }
    s[t] = sum;
    __syncthreads();
    for (int off = 1; off < 1024; off <<= 1) {
        int v = (t >= off) ? s[t - off] : 0;
        __syncthreads();
        s[t] += v;
        __syncthreads();
    }
    int excl = (t == 0) ? 0 : s[t - 1];
#pragma unroll
    for (int i = 0; i < PER; ++i) { offsets[base + i] = excl; excl += local[i]; }
}

// Scatter + setup: computes per-LOR ray record once, writes SORTED arrays.
__global__ void scatter_kernel(const float* __restrict__ lors,
                               const int* __restrict__ tmp,
                               int* __restrict__ offsets,
                               float4* __restrict__ recS,   // {tmin,span,L,pack}
                               float4* __restrict__ ls8,    // 2 per LOR
                               int n) {
#pragma clang fp contract(off)
    int i = blockIdx.x * 256 + threadIdx.x;
    if (i >= n) return;
    const float* lp = lors + (size_t)i * 7;
    float p1x = lp[0], p1y = lp[1], p1z = lp[2];
    float p2x = lp[3], p2y = lp[4], p2z = lp[5];
    float tt = lp[6];
    float dx = p2x - p1x, dy = p2y - p1y, dz = p2z - p1z;
    float L = sqrtf(((dx * dx) + (dy * dy)) + (dz * dz));

    float tmin, tmax;
    slab_clip(p1x, p1y, p1z, dx, dy, dz, tmin, tmax);

    float span, recL;
    int jlo, jhi;
    if (!(tmax > tmin) || !(L > 0.f)) {
        // invalid or degenerate (L==0 => step==0 => out 0 regardless)
        tmin = 0.f; span = 0.f; recL = 0.f; jlo = 0; jhi = -1;
    } else {
        span = tmax - tmin;
        recL = L;
        // Closed-form sample range of TOF window, +-2 slop (validated R4-R6);
        // exact per-sample test retained in proj -> identical sample set.
        const float tlo = 0.5f + (tt - 90.0f) / L;
        const float thi = 0.5f + (tt + 90.0f) / L;
        float jl = ((tlo - tmin) / span) * 128.0f - 0.5f;
        float jh = ((thi - tmin) / span) * 128.0f - 0.5f;
        jl = fminf(fmaxf(jl - 2.0f, 0.0f), 127.0f);
        jh = fminf(fmaxf(jh + 2.0f, -1.0f), 127.0f);
        jlo = (int)jl;
        jhi = (int)ceilf(jh);
        if (jhi > 127) jhi = 127;
    }

    int slot = atomicAdd(&offsets[tmp[i]], 1);
    int pk = (jlo << 16) | (jhi & 0xFFFF);
    recS[slot] = make_float4(tmin, span, recL, __int_as_float(pk));
    ls8[2 * slot + 0] = make_float4(p1x, p1y, p1z, p2x);
    ls8[2 * slot + 1] = make_float4(p2y, p2z, tt, __int_as_float(i));
}

__global__ __launch_bounds__(256) void proj_kernel(
    const float* __restrict__ image,
    const float4* __restrict__ recS,
    const float4* __restrict__ ls8,
    float* __restrict__ out,
    int n_lors, int chunks)
{
#pragma clang fp contract(off)
    // XCD swizzle: block b -> XCD (b&7) works the (b&7)-th chunk of sorted order
    const int b = blockIdx.x;
    const int sb = (b & 7) * chunks + (b >> 3);
    const int idx = sb * 256 + (int)threadIdx.x;
    const int gid = idx >> 3;          // sorted LOR slot
    const int s   = idx & 7;           // sub-lane 0..7
    if (gid >= n_lors) return;

    const float4 a  = ls8[2 * gid + 0];
    const float4 c  = ls8[2 * gid + 1];
    const float4 r  = recS[gid];
    const float p1x = a.x, p1y = a.y, p1z = a.z;
    const float dx = a.w - p1x, dy = c.x - p1y, dz = c.y - p1z;
    const float ttof = c.z;
    const int   orig = __float_as_int(c.w);
    const float tmin = r.x, span = r.y, L = r.z;
    const int   pk   = __float_as_int(r.w);
    const int   jlo  = pk >> 16;
    const int   jhi  = (int)(short)(pk & 0xFFFF);

    // Affine constants (approx path — explicit fmaf OK, bound proven):
    //   Q(alpha)  = C0 + alpha*C1  ~=  ((p1 + t*d) + 200)*0.32 chain
    //   dev(alpha)= D0 + alpha*D1
    // alpha = j + 0.5 (exact fp32 for j in [0,128]).
    const float sd  = span * 0.0078125f;            // span/128 (exact scale)
    const float C1x = (sd * dx) * 0.32f;
    const float C1y = (sd * dy) * 0.32f;
    const float C1z = (sd * dz) * 0.32f;
    const float C0x = ((p1x + (tmin * dx)) + 200.0f) * 0.32f;
    const float C0y = ((p1y + (tmin * dy)) + 200.0f) * 0.32f;
    const float C0z = ((p1z + (tmin * dz)) + 200.0f) * 0.32f;
    const float D1  = sd * L;
    const float D0  = ((tmin - 0.5f) * L) - ttof;

    float acc0 = 0.0f, acc1 = 0.0f;

    // One sample at fp32 alpha = j+0.5 (exact). Guarded affine voxel path,
    // rare fallback recomputes the FULL exact unfused reference chain.
    auto sample = [&](float al, float& acc) {
        const float Qx = fmaf(al, C1x, C0x);
        const float Qy = fmaf(al, C1y, C0y);
        const float Qz = fmaf(al, C1z, C0z);
        float fx = floorf(Qx), fy = floorf(Qy), fz = floorf(Qz);
        const float rx = Qx - fx, ry = Qy - fy, rz = Qz - fz;
        const float rmn = fminf(fminf(rx, ry), rz);    // v_min3
        const float rmx = fmaxf(fmaxf(rx, ry), rz);    // v_max3
        if (__builtin_expect(rmn < 1e-3f || rmx > 0.999f, 0)) {
            // EXACT reference chain (unfused, exact-rn, plain '/'):
            const float fr = al * 0.0078125f;          // ((float)j+0.5f)/128
            const float t  = tmin + (fr * span);
            const float ex = p1x + (t * dx);
            const float ey = p1y + (t * dy);
            const float ez = p1z + (t * dz);
            fx = floorf((ex + 200.0f) / 3.125f);
            fy = floorf((ey + 200.0f) / 3.125f);
            fz = floorf((ez + 200.0f) / 3.125f);
        }
        // clamp in float (v_med3), then convert
        const int vx = (int)fminf(fmaxf(fx, 0.0f), 127.0f);
        const int vy = (int)fminf(fmaxf(fy, 0.0f), 127.0f);
        const int vz = (int)fminf(fmaxf(fz, 0.0f), 127.0f);
        const float val = image[(((vx << 7) | vy) << 7) | vz];

        const float dev = fmaf(al, D1, D0);            // weight path: approx OK
        const float w = (fabsf(dev) <= 90.0f)
            ? 0.06649038f * __expf((dev * dev) * (-5.5555556e-4f)) : 0.0f;
        acc = fmaf(val, w, acc);
    };

    float al = (float)(jlo + s) + 0.5f;                // exact
    int j = jlo + s;
    for (; j + SPL <= jhi; j += 2 * SPL) {
        sample(al, acc0);
        sample(al + 8.0f, acc1);                       // exact (int+0.5 range)
        al += 16.0f;
    }
    if (j <= jhi) sample(al, acc0);                    // <=1 remainder

    float acc = acc0 + acc1;   // summation order free (validated R4/R5/R6)

    // combine 8 sub-lanes
    acc += __shfl_xor(acc, 1, 64);
    acc += __shfl_xor(acc, 2, 64);
    acc += __shfl_xor(acc, 4, 64);

    if (s == 0) {
        // step = (span*L)/128: *0.0078125f bit-identical
        const float step = (span * L) * 0.0078125f;
        out[orig] = acc * step;
    }
}

// Fallback (ws too small): self-contained thread-per-LOR, unsorted. Correct
// but slower; only taken if the harness workspace is < ~11 MB.
__global__ __launch_bounds__(256) void proj_fallback(
    const float* __restrict__ image,
    const float* __restrict__ lors,
    float* __restrict__ out, int n_lors)
{
#pragma clang fp contract(off)
    const int lor = blockIdx.x * 256 + threadIdx.x;
    if (lor >= n_lors) return;
    const float* lp = lors + (size_t)lor * 7;
    const float p1x = lp[0], p1y = lp[1], p1z = lp[2];
    const float dx = lp[3] - p1x, dy = lp[4] - p1y, dz = lp[5] - p1z;
    const float ttof = lp[6];
    const float L = sqrtf(((dx * dx) + (dy * dy)) + (dz * dz));
    float tmin, tmax;
    slab_clip(p1x, p1y, p1z, dx, dy, dz, tmin, tmax);
    const float span = fmaxf(tmax - tmin, 0.0f);
    if (!(tmax > tmin)) { out[lor] = 0.0f; return; }
    float acc = 0.0f;
    for (int j = 0; j < 128; ++j) {
        const float frac = ((float)j + 0.5f) * 0.0078125f;
        const float t = tmin + (frac * span);
        const float dev = ((t - 0.5f) * L) - ttof;
        if (fabsf(dev) <= 90.0f) {
            const float px = p1x + (t * dx);
            const float py = p1y + (t * dy);
            const float pz = p1z + (t * dz);
            const int vx = vox_of(px + 200.0f);
            const int vy = vox_of(py + 200.0f);
            const int vz = vox_of(pz + 200.0f);
            const float val = image[(((vx << 7) | vy) << 7) | vz];
            const float w = 0.06649038f *
                            __expf((dev * dev) * (-5.5555556e-4f));
            acc += val * w;
        }
    }
    out[lor] = acc * ((span * L) * 0.0078125f);
}

extern "C" void kernel_launch(void* const* d_in, const int* in_sizes, int n_in,
                              void* d_out, int out_size, void* d_ws, size_t ws_size,
                              hipStream_t stream) {
    const float* image = (const float*)d_in[0];   // 128^3 fp32
    const float* lors  = (const float*)d_in[1];   // N x 7 fp32
    float* out = (float*)d_out;                   // N fp32
    const int n = in_sizes[1] / 7;

    // ws layout: counts[NBUCK] | offsets[NBUCK] | tmp[n] | (16B align)
    //            recS[n]x16B | ls8[2n]x16B
    char* base = (char*)d_ws;
    int* counts  = (int*)base;
    int* offsets = counts + NBUCK;
    int* tmp     = offsets + NBUCK;
    size_t off = (size_t)(2 * NBUCK + n) * sizeof(int);
    off = (off + 15) & ~(size_t)15;
    float4* recS = (float4*)(base + off);
    float4* ls8  = (float4*)(base + off + (size_t)n * 16);
    const size_t need = off + (size_t)n * 48;
    const bool do_sort = (ws_size >= need);

    if (do_sort) {
        hipMemsetAsync(counts, 0, NBUCK * sizeof(int), stream);
        bucket_kernel<<<(n + 255) / 256, 256, 0, stream>>>(lors, counts, tmp, n);
        scan_kernel<<<1, 1024, 0, stream>>>(counts, offsets);
        scatter_kernel<<<(n + 255) / 256, 256, 0, stream>>>(lors, tmp, offsets,
                                                            recS, ls8, n);
        const int nthreads = n * SPL;
        const int nblocks = (nthreads + 255) / 256;
        const int nb8 = ((nblocks + 7) / 8) * 8;
        proj_kernel<<<nb8, 256, 0, stream>>>(image, recS, ls8, out, n, nb8 >> 3);
    } else {
        proj_fallback<<<(n + 255) / 256, 256, 0, stream>>>(image, lors, out, n);
    }
}

// Round 4
// 138.471 us; speedup vs baseline: 1.0308x; 1.0096x over previous
//
#include <hip/hip_runtime.h>
#include <math.h>

// TOF PET forward projection.
// History: R3 97us proj, FETCH 215MB (L2 thrash) -> R4 Morton sort: FETCH
// 26MB -> R5 bucket atomic-storm bug -> R6 fix + 4 lanes/LOR: proj 67us ->
// R7 sorted record materialization + 8 lanes/LOR: proj 50us -> R8 exact-fast-
// path voxel divide: proj 44.5us, VALUBusy 74->54% -> R9 2x unroll +
// branchless: NEUTRAL -> R10 affine index fast path: NEUTRAL (45us, VALU 57).
// Three different VALU reductions all landed at 45us => proj is bound by the
// scattered image GATHER (one L1 transaction per distinct 64B line per wave
// load; linear layout lines are 1x1x16-voxel needles => ~6-8 lines per
// 8-sample segment).
// R11: BRICK the image: 2x2x4-voxel bricks = 16 floats = exactly one 64B
// line (6.25x6.25x12.5mm cube-ish). Distinct lines/segment ~6.6 -> ~4.5 plus
// cross-LOR sharing near the TOF center. vx/vy/vz computation UNTOUCHED
// (bit-identical indices; only the load address is bijectively remapped) =>
// output bit-for-bit identical to R10. Repack kernel: 16MB traffic ~4us.
// Index-path math (affine guard + exact fallback, scatter/bucket) is
// STRICTLY UNFUSED exact-rn f32 — DO NOT approximate or contract (R0-R2:
// voxel flips => absmax 0.14 > 0.071). Affine path bound proven in R10:
// floor(Q)==floor(ref) unless frac(Q) within 1e-3 of integer -> exact chain
// fallback (~2e-3/coord). Summation order free (validated R4/R5/R6).

#define NB_POS 4096          // 16^3 Morton cells, 25 mm
#define NCLS   8             // window-length classes (16-sample bins)
#define NBUCK  (NB_POS * NCLS)
#define SPL    8             // lanes per LOR

__device__ __forceinline__ int morton4(int x, int y, int z) {
    int m = 0;
#pragma unroll
    for (int b = 0; b < 4; ++b) {
        m |= ((x >> b) & 1) << (3 * b + 0);
        m |= ((y >> b) & 1) << (3 * b + 1);
        m |= ((z >> b) & 1) << (3 * b + 2);
    }
    return m;
}

// Voxel index for the fallback kernel: bit-identical to
// (int)floorf(xs / 3.125f) (R8-validated exact-fast-path).
__device__ __forceinline__ int vox_of(float xs) {
#pragma clang fp contract(off)
    float q  = xs * 0.32f;
    float fq = floorf(q);
    float f  = q - fq;                      // exact (Sterbenz-range)
    if (__builtin_expect(f < 1e-4f || f > 0.9999f, 0)) {
        fq = floorf(xs / 3.125f);           // exact rn div — rare path
    }
    return min(max((int)fq, 0), 127);
}

// Slab clip shared by bucket/scatter (strictly unfused, exact rn divs —
// produces the tmin/span the reference sees).
__device__ __forceinline__ void slab_clip(
    float p1x, float p1y, float p1z, float dx, float dy, float dz,
    float& tmin, float& tmax)
{
    const float eps = 1e-8f;
    float sdx = (fabsf(dx) < eps) ? eps : dx;
    float sdy = (fabsf(dy) < eps) ? eps : dy;
    float sdz = (fabsf(dz) < eps) ? eps : dz;
    float tax = (-200.f - p1x) / sdx, tbx = (200.f - p1x) / sdx;
    float tay = (-200.f - p1y) / sdy, tby = (200.f - p1y) / sdy;
    float taz = (-200.f - p1z) / sdz, tbz = (200.f - p1z) / sdz;
    tmin = fmaxf(fmaxf(fmaxf(fminf(tax, tbx), fminf(tay, tby)),
                       fminf(taz, tbz)), 0.f);
    tmax = fminf(fminf(fminf(fmaxf(tax, tbx), fmaxf(tay, tby)),
                       fmaxf(taz, tbz)), 1.f);
}

__global__ void bucket_kernel(const float* __restrict__ lors,
                              int* __restrict__ counts,
                              int* __restrict__ tmp, int n) {
#pragma clang fp contract(off)
    int i = blockIdx.x * 256 + threadIdx.x;
    if (i >= n) return;
    const float* lp = lors + (size_t)i * 7;
    float p1x = lp[0], p1y = lp[1], p1z = lp[2];
    float dx = lp[3] - p1x, dy = lp[4] - p1y, dz = lp[5] - p1z;
    float tt = lp[6];
    float L = sqrtf(((dx * dx) + (dy * dy)) + (dz * dz));

    float tmin, tmax;
    slab_clip(p1x, p1y, p1z, dx, dy, dz, tmin, tmax);

    unsigned key;
    if (!(tmax > tmin) || !(L > 0.f)) {
        // Invalids: spread uniformly (kills R5's one-bucket atomic storm).
        key = (unsigned)i & (NBUCK - 1);
    } else {
        float span = tmax - tmin;
        // TOF-center cell (sort key only; approx math OK here)
        float tc = fminf(fmaxf(0.5f + tt / L, tmin), tmax);
        float px = p1x + tc * dx, py = p1y + tc * dy, pz = p1z + tc * dz;
        int cx = (int)fminf(fmaxf((px + 200.f) * 0.04f, 0.f), 15.f);
        int cy = (int)fminf(fmaxf((py + 200.f) * 0.04f, 0.f), 15.f);
        int cz = (int)fminf(fmaxf((pz + 200.f) * 0.04f, 0.f), 15.f);
        // window length -> 3-bit class (16-sample bins): wave-uniform trips
        float jl = ((0.5f + (tt - 90.f) / L) - tmin) / span * 128.f;
        float jh = ((0.5f + (tt + 90.f) / L) - tmin) / span * 128.f;
        jl = fmaxf(jl, 0.f); jh = fminf(jh, 128.f);
        float wlen = fmaxf(jh - jl, 0.f);
        int cls = min(NCLS - 1, (int)(wlen * (1.f / 16.f)));
        key = ((unsigned)morton4(cx, cy, cz) << 3) | (unsigned)cls;
    }
    atomicAdd(&counts[key], 1);
    tmp[i] = (int)key;
}

__global__ void scan_kernel(const int* __restrict__ counts,
                            int* __restrict__ offsets) {
    __shared__ int s[1024];
    int t = threadIdx.x;
    const int PER = NBUCK / 1024;
    int base = t * PER;
    int local[PER];
    int sum = 0;
#pragma unroll
    for (int i = 0; i < PER; ++i) { local[i] = counts[base + i]; sum += local[i]; }
    s[t] = sum;
    __syncthreads();
    for (int off = 1; off < 1024; off <<= 1) {
        int v = (t >= off) ? s[t - off] : 0;
        __syncthreads();
        s[t] += v;
        __syncthreads();
    }
    int excl = (t == 0) ? 0 : s[t - 1];
#pragma unroll
    for (int i = 0; i < PER; ++i) { offsets[base + i] = excl; excl += local[i]; }
}

// Scatter + setup: computes per-LOR ray record once, writes SORTED arrays.
__global__ void scatter_kernel(const float* __restrict__ lors,
                               const int* __restrict__ tmp,
                               int* __restrict__ offsets,
                               float4* __restrict__ recS,   // {tmin,span,L,pack}
                               float4* __restrict__ ls8,    // 2 per LOR
                               int n) {
#pragma clang fp contract(off)
    int i = blockIdx.x * 256 + threadIdx.x;
    if (i >= n) return;
    const float* lp = lors + (size_t)i * 7;
    float p1x = lp[0], p1y = lp[1], p1z = lp[2];
    float p2x = lp[3], p2y = lp[4], p2z = lp[5];
    float tt = lp[6];
    float dx = p2x - p1x, dy = p2y - p1y, dz = p2z - p1z;
    float L = sqrtf(((dx * dx) + (dy * dy)) + (dz * dz));

    float tmin, tmax;
    slab_clip(p1x, p1y, p1z, dx, dy, dz, tmin, tmax);

    float span, recL;
    int jlo, jhi;
    if (!(tmax > tmin) || !(L > 0.f)) {
        // invalid or degenerate (L==0 => step==0 => out 0 regardless)
        tmin = 0.f; span = 0.f; recL = 0.f; jlo = 0; jhi = -1;
    } else {
        span = tmax - tmin;
        recL = L;
        // Closed-form sample range of TOF window, +-2 slop (validated R4-R6);
        // exact per-sample test retained in proj -> identical sample set.
        const float tlo = 0.5f + (tt - 90.0f) / L;
        const float thi = 0.5f + (tt + 90.0f) / L;
        float jl = ((tlo - tmin) / span) * 128.0f - 0.5f;
        float jh = ((thi - tmin) / span) * 128.0f - 0.5f;
        jl = fminf(fmaxf(jl - 2.0f, 0.0f), 127.0f);
        jh = fminf(fmaxf(jh + 2.0f, -1.0f), 127.0f);
        jlo = (int)jl;
        jhi = (int)ceilf(jh);
        if (jhi > 127) jhi = 127;
    }

    int slot = atomicAdd(&offsets[tmp[i]], 1);
    int pk = (jlo << 16) | (jhi & 0xFFFF);
    recS[slot] = make_float4(tmin, span, recL, __int_as_float(pk));
    ls8[2 * slot + 0] = make_float4(p1x, p1y, p1z, p2x);
    ls8[2 * slot + 1] = make_float4(p2y, p2z, tt, __int_as_float(i));
}

// Repack 128^3 fp32 image into 2x2x4-voxel bricks (16 floats = one 64B line).
// Thread = OUTPUT index (coalesced writes); reads pull 4 lines per wave.
// brick grid: 64 x 64 x 32; within brick: ox(1b) oy(1b) oz(2b).
__global__ __launch_bounds__(256) void brickify_kernel(
    const float* __restrict__ image, float* __restrict__ bimg) {
    const int o = blockIdx.x * 256 + threadIdx.x;   // 0 .. 128^3-1
    const int off = o & 15;
    const int brick = o >> 4;
    const int bz = brick & 31;
    const int t  = brick >> 5;
    const int by = t & 63;
    const int bx = t >> 6;
    const int oz = off & 3, oy = (off >> 2) & 1, ox = off >> 3;
    const int vx = (bx << 1) | ox, vy = (by << 1) | oy, vz = (bz << 2) | oz;
    bimg[o] = image[(((vx << 7) | vy) << 7) | vz];
}

template <bool BRICK>
__global__ __launch_bounds__(256) void proj_kernel(
    const float* __restrict__ img,     // bricked if BRICK, else linear
    const float4* __restrict__ recS,
    const float4* __restrict__ ls8,
    float* __restrict__ out,
    int n_lors, int chunks)
{
#pragma clang fp contract(off)
    // XCD swizzle: block b -> XCD (b&7) works the (b&7)-th chunk of sorted order
    const int b = blockIdx.x;
    const int sb = (b & 7) * chunks + (b >> 3);
    const int idx = sb * 256 + (int)threadIdx.x;
    const int gid = idx >> 3;          // sorted LOR slot
    const int s   = idx & 7;           // sub-lane 0..7
    if (gid >= n_lors) return;

    const float4 a  = ls8[2 * gid + 0];
    const float4 c  = ls8[2 * gid + 1];
    const float4 r  = recS[gid];
    const float p1x = a.x, p1y = a.y, p1z = a.z;
    const float dx = a.w - p1x, dy = c.x - p1y, dz = c.y - p1z;
    const float ttof = c.z;
    const int   orig = __float_as_int(c.w);
    const float tmin = r.x, span = r.y, L = r.z;
    const int   pk   = __float_as_int(r.w);
    const int   jlo  = pk >> 16;
    const int   jhi  = (int)(short)(pk & 0xFFFF);

    // Affine constants (approx path — explicit fmaf OK, bound proven R10):
    //   Q(alpha)  = C0 + alpha*C1  ~=  ((p1 + t*d) + 200)*0.32 chain
    //   dev(alpha)= D0 + alpha*D1
    // alpha = j + 0.5 (exact fp32 for j in [0,128]).
    const float sd  = span * 0.0078125f;            // span/128 (exact scale)
    const float C1x = (sd * dx) * 0.32f;
    const float C1y = (sd * dy) * 0.32f;
    const float C1z = (sd * dz) * 0.32f;
    const float C0x = ((p1x + (tmin * dx)) + 200.0f) * 0.32f;
    const float C0y = ((p1y + (tmin * dy)) + 200.0f) * 0.32f;
    const float C0z = ((p1z + (tmin * dz)) + 200.0f) * 0.32f;
    const float D1  = sd * L;
    const float D0  = ((tmin - 0.5f) * L) - ttof;

    float acc0 = 0.0f, acc1 = 0.0f;

    // One sample at fp32 alpha = j+0.5 (exact). Guarded affine voxel path,
    // rare fallback recomputes the FULL exact unfused reference chain.
    auto sample = [&](float al, float& acc) {
        const float Qx = fmaf(al, C1x, C0x);
        const float Qy = fmaf(al, C1y, C0y);
        const float Qz = fmaf(al, C1z, C0z);
        float fx = floorf(Qx), fy = floorf(Qy), fz = floorf(Qz);
        const float rx = Qx - fx, ry = Qy - fy, rz = Qz - fz;
        const float rmn = fminf(fminf(rx, ry), rz);    // v_min3
        const float rmx = fmaxf(fmaxf(rx, ry), rz);    // v_max3
        if (__builtin_expect(rmn < 1e-3f || rmx > 0.999f, 0)) {
            // EXACT reference chain (unfused, exact-rn, plain '/'):
            const float fr = al * 0.0078125f;          // ((float)j+0.5f)/128
            const float t  = tmin + (fr * span);
            const float ex = p1x + (t * dx);
            const float ey = p1y + (t * dy);
            const float ez = p1z + (t * dz);
            fx = floorf((ex + 200.0f) / 3.125f);
            fy = floorf((ey + 200.0f) / 3.125f);
            fz = floorf((ez + 200.0f) / 3.125f);
        }
        // clamp in float (v_med3), then convert
        const int vx = (int)fminf(fmaxf(fx, 0.0f), 127.0f);
        const int vy = (int)fminf(fmaxf(fy, 0.0f), 127.0f);
        const int vz = (int)fminf(fmaxf(fz, 0.0f), 127.0f);

        int vidx;
        if (BRICK) {
            // (bx*64+by)*32+bz bricks of 16; off = ox*8+oy*4+oz
            vidx = ((((((vx >> 1) << 6) | (vy >> 1)) << 5) | (vz >> 2)) << 4)
                   | ((vx & 1) << 3) | ((vy & 1) << 2) | (vz & 3);
        } else {
            vidx = (((vx << 7) | vy) << 7) | vz;
        }
        const float val = img[vidx];

        const float dev = fmaf(al, D1, D0);            // weight path: approx OK
        const float w = (fabsf(dev) <= 90.0f)
            ? 0.06649038f * __expf((dev * dev) * (-5.5555556e-4f)) : 0.0f;
        acc = fmaf(val, w, acc);
    };

    float al = (float)(jlo + s) + 0.5f;                // exact
    int j = jlo + s;
    for (; j + SPL <= jhi; j += 2 * SPL) {
        sample(al, acc0);
        sample(al + 8.0f, acc1);                       // exact (int+0.5 range)
        al += 16.0f;
    }
    if (j <= jhi) sample(al, acc0);                    // <=1 remainder

    float acc = acc0 + acc1;   // summation order free (validated R4/R5/R6)

    // combine 8 sub-lanes
    acc += __shfl_xor(acc, 1, 64);
    acc += __shfl_xor(acc, 2, 64);
    acc += __shfl_xor(acc, 4, 64);

    if (s == 0) {
        // step = (span*L)/128: *0.0078125f bit-identical
        const float step = (span * L) * 0.0078125f;
        out[orig] = acc * step;
    }
}

// Fallback (ws too small): self-contained thread-per-LOR, unsorted. Correct
// but slower; only taken if the harness workspace is < ~11 MB.
__global__ __launch_bounds__(256) void proj_fallback(
    const float* __restrict__ image,
    const float* __restrict__ lors,
    float* __restrict__ out, int n_lors)
{
#pragma clang fp contract(off)
    const int lor = blockIdx.x * 256 + threadIdx.x;
    if (lor >= n_lors) return;
    const float* lp = lors + (size_t)lor * 7;
    const float p1x = lp[0], p1y = lp[1], p1z = lp[2];
    const float dx = lp[3] - p1x, dy = lp[4] - p1y, dz = lp[5] - p1z;
    const float ttof = lp[6];
    const float L = sqrtf(((dx * dx) + (dy * dy)) + (dz * dz));
    float tmin, tmax;
    slab_clip(p1x, p1y, p1z, dx, dy, dz, tmin, tmax);
    const float span = fmaxf(tmax - tmin, 0.0f);
    if (!(tmax > tmin)) { out[lor] = 0.0f; return; }
    float acc = 0.0f;
    for (int j = 0; j < 128; ++j) {
        const float frac = ((float)j + 0.5f) * 0.0078125f;
        const float t = tmin + (frac * span);
        const float dev = ((t - 0.5f) * L) - ttof;
        if (fabsf(dev) <= 90.0f) {
            const float px = p1x + (t * dx);
            const float py = p1y + (t * dy);
            const float pz = p1z + (t * dz);
            const int vx = vox_of(px + 200.0f);
            const int vy = vox_of(py + 200.0f);
            const int vz = vox_of(pz + 200.0f);
            const float val = image[(((vx << 7) | vy) << 7) | vz];
            const float w = 0.06649038f *
                            __expf((dev * dev) * (-5.5555556e-4f));
            acc += val * w;
        }
    }
    out[lor] = acc * ((span * L) * 0.0078125f);
}

extern "C" void kernel_launch(void* const* d_in, const int* in_sizes, int n_in,
                              void* d_out, int out_size, void* d_ws, size_t ws_size,
                              hipStream_t stream) {
    const float* image = (const float*)d_in[0];   // 128^3 fp32
    const float* lors  = (const float*)d_in[1];   // N x 7 fp32
    float* out = (float*)d_out;                   // N fp32
    const int n = in_sizes[1] / 7;

    // ws layout: counts[NBUCK] | offsets[NBUCK] | tmp[n] | (16B align)
    //            recS[n]x16B | ls8[2n]x16B | (256B align) bimg[128^3]
    char* base = (char*)d_ws;
    int* counts  = (int*)base;
    int* offsets = counts + NBUCK;
    int* tmp     = offsets + NBUCK;
    size_t off = (size_t)(2 * NBUCK + n) * sizeof(int);
    off = (off + 15) & ~(size_t)15;
    float4* recS = (float4*)(base + off);
    float4* ls8  = (float4*)(base + off + (size_t)n * 16);
    const size_t need = off + (size_t)n * 48;
    size_t bimg_off = (need + 255) & ~(size_t)255;
    const size_t IMG_BYTES = (size_t)128 * 128 * 128 * 4;
    const size_t need_brick = bimg_off + IMG_BYTES;
    float* bimg = (float*)(base + bimg_off);

    const bool do_sort  = (ws_size >= need);
    const bool do_brick = (ws_size >= need_brick);

    if (do_sort) {
        hipMemsetAsync(counts, 0, NBUCK * sizeof(int), stream);
        bucket_kernel<<<(n + 255) / 256, 256, 0, stream>>>(lors, counts, tmp, n);
        scan_kernel<<<1, 1024, 0, stream>>>(counts, offsets);
        scatter_kernel<<<(n + 255) / 256, 256, 0, stream>>>(lors, tmp, offsets,
                                                            recS, ls8, n);
        const int nthreads = n * SPL;
        const int nblocks = (nthreads + 255) / 256;
        const int nb8 = ((nblocks + 7) / 8) * 8;
        if (do_brick) {
            brickify_kernel<<<(128 * 128 * 128) / 256, 256, 0, stream>>>(image,
                                                                         bimg);
            proj_kernel<true><<<nb8, 256, 0, stream>>>(bimg, recS, ls8, out, n,
                                                       nb8 >> 3);
        } else {
            proj_kernel<false><<<nb8, 256, 0, stream>>>(image, recS, ls8, out, n,
                                                        nb8 >> 3);
        }
    } else {
        proj_fallback<<<(n + 255) / 256, 256, 0, stream>>>(image, lors, out, n);
    }
}